// Round 12
// baseline (471.550 us; speedup 1.0000x reference)
//
#include <hip/hip_runtime.h>
#include <hip/hip_cooperative_groups.h>
#include <math.h>

namespace cg = cooperative_groups;

#define TPB 256

typedef unsigned short u16;
typedef short bf16x8 __attribute__((ext_vector_type(8)));
typedef unsigned short u16x4 __attribute__((ext_vector_type(4)));
typedef float f32x4 __attribute__((ext_vector_type(4)));

__device__ __forceinline__ u16 f2bf(float x) {
    unsigned u = __float_as_uint(x);
    unsigned r = u + 0x7fffu + ((u >> 16) & 1u);
    return (u16)(r >> 16);
}
__device__ __forceinline__ float bf2f(u16 h) {
    return __uint_as_float(((unsigned)h) << 16);
}
// k-permutation within 32-chunk (half-split fragment layout); applied to BOTH
// operands of every GEMM -> dot over k is permutation-invariant.
__device__ __forceinline__ int pos32(int kk) {
    return ((kk >> 2) & 3) * 8 + (kk >> 4) * 4 + (kk & 3);
}
__device__ __forceinline__ int ipos32(int p5) {
    return 16 * ((p5 >> 2) & 1) + 4 * (p5 >> 3) + (p5 & 3);
}

// Tile-blocked-swizzled (TBS) storage: matrix[R][K] bf16 as 64x64 tiles, tile
// (tr,tk) = 8 KB at ((tr*(K/64)+tk)<<13); element (row,p) at byte
// row*128 + (((p>>3)<<4) ^ ((row&7)<<4)) + (p&7)*2  == the LDS image.

#if defined(__has_builtin)
#if __has_builtin(__builtin_amdgcn_global_load_lds)
#define HAS_GLL 1
#endif
#endif
#ifndef HAS_GLL
#define HAS_GLL 0
#endif

__device__ __forceinline__ void gl16(const char* g, char* l) {
#if HAS_GLL
    __builtin_amdgcn_global_load_lds(
        (const __attribute__((address_space(1))) void*)(unsigned long long)g,
        (__attribute__((address_space(3))) void*)(unsigned int)(unsigned long long)l,
        16, 0, 0);
#else
    *(int4*)l = *(const int4*)g;
#endif
}

struct MegaParams {
    const float* up; const float* uc; const float* wa; const float* W;
    u16* upw3; u16* ucb; u16* ucT; u16* upT;
    float* rpart; float* cpart; float* zbuf; float* fpart; float* fpart2;
    u16* Sp; u16* E; u16* ET;
    float* rowsum; float* colsum;
    const float* bias; float* out;
    int m, n, d;
};

// One cooperative kernel, 512 blocks x 256 threads; phases split by grid.sync().
__global__ __launch_bounds__(TPB, 2) void mega_kernel(MegaParams P) {
    cg::grid_group grid = cg::this_grid();
    __shared__ __align__(16) char smem[25600];
    int b = blockIdx.x, tid = threadIdx.x;
    int m = P.m, n = P.n, d = P.d;
    int ntk = d >> 6;  // 32

    // ================= phase 1: prep (2 tiles per block: uc then up) =================
    {
        float* t = (float*)smem;                    // 64*65 f32 = 16640 B
        float* wred = (float*)(smem + 16640);       // 4 f32
        if (b < 8) { int idx = b * TPB + tid; if (idx < 2 * m) P.zbuf[idx] = 0.f; }
        #pragma unroll 1
        for (int half = 0; half < 2; ++half) {
            __syncthreads();
            const float* src; u16* dstT; u16* dstR; float* bpart; int rows; int isUp;
            if (half == 0) { src = P.uc; dstT = P.ucT; dstR = P.ucb;  bpart = P.cpart; rows = n; isUp = 0; }
            else           { src = P.up; dstT = P.upT; dstR = P.upw3; bpart = P.rpart; rows = m; isUp = 1; }
            int tt = b;
            int c0 = (tt % ntk) * 64;   // k-range
            int r0 = (tt / ntk) * 64;   // sample-row range
            #pragma unroll
            for (int it = 0; it < 4; ++it) {
                int rr = (tid >> 4) + it * 16;
                int cc = (tid & 15) * 4;
                float4 v = *(const float4*)(src + (size_t)(r0 + rr) * d + c0 + cc);
                t[(cc + 0) * 65 + rr] = v.x;
                t[(cc + 1) * 65 + rr] = v.y;
                t[(cc + 2) * 65 + rr] = v.z;
                t[(cc + 3) * 65 + rr] = v.w;
            }
            __syncthreads();
            // transposed TBS output
            {
                char* tbase = (char*)dstT + (((size_t)(c0 >> 6) * (rows >> 6) + (r0 >> 6)) << 13);
                #pragma unroll
                for (int it = 0; it < 2; ++it) {
                    int id = tid + it * TPB;
                    int kc = id >> 3;
                    int s = id & 7;
                    u16 outv[8];
                    #pragma unroll
                    for (int e = 0; e < 8; ++e) {
                        int p = s * 8 + e;
                        int jloc = 32 * (p >> 5) + ipos32(p & 31);
                        outv[e] = f2bf(t[kc * 65 + jloc]);
                    }
                    char* pp = tbase + kc * 128 + ((s * 16) ^ ((kc & 7) << 4));
                    *(u16x4*)pp = *(u16x4*)&outv[0];
                    *(u16x4*)(pp + 8) = *(u16x4*)&outv[4];
                }
            }
            // row-major TBS output (k permuted), *w3 for up
            {
                char* rbase = (char*)dstR + (((size_t)(r0 >> 6) * ntk + (c0 >> 6)) << 13);
                int rr = tid >> 2;
                int cbase = (tid & 3) * 16;
                #pragma unroll
                for (int grp = 0; grp < 4; ++grp) {
                    int kl = cbase + grp * 4;
                    u16x4 o;
                    #pragma unroll
                    for (int e = 0; e < 4; ++e) {
                        float val = t[(kl + e) * 65 + rr];
                        if (isUp) val *= P.wa[2 * d + c0 + kl + e];
                        o[e] = f2bf(val);
                    }
                    int pl = (kl & ~31) + pos32(kl & 31);
                    *(u16x4*)(rbase + rr * 128 + (((pl >> 3) << 4) ^ ((rr & 7) << 4)) + (pl & 7) * 2) = o;
                }
            }
            // bias partials
            {
                int rr = tid >> 2;
                int kseg = tid & 3;
                const float* w = P.wa + (isUp ? 0 : d) + c0;
                float acc = 0.f;
                #pragma unroll
                for (int kk = 0; kk < 16; ++kk) {
                    int k = kseg * 16 + kk;
                    acc += t[k * 65 + rr] * w[k];
                }
                acc += __shfl_xor(acc, 1);
                acc += __shfl_xor(acc, 2);
                if (kseg == 0) bpart[(size_t)(c0 >> 6) * rows + r0 + rr] = acc;
            }
            // term1 partial (up tiles only)
            if (isUp) {
                int rr = tid >> 2;
                int kseg = tid & 3;
                const float* w0r = P.W + (size_t)(r0 + rr) * 4 * d + c0 + kseg * 16;
                float acc = 0.f;
                #pragma unroll
                for (int kk = 0; kk < 16; ++kk) acc += t[(kseg * 16 + kk) * 65 + rr] * w0r[kk];
                #pragma unroll
                for (int off = 32; off > 0; off >>= 1) acc += __shfl_down(acc, off);
                if ((tid & 63) == 0) wred[tid >> 6] = acc;
                __syncthreads();
                if (tid == 0) P.fpart[tt] = wred[0] + wred[1] + wred[2] + wred[3];
            }
        }
    }
    __threadfence();
    grid.sync();

    // ================= phase 2: gemmS partials (KSPLIT=4), 128x64 tile =================
    {
        u16* sA = (u16*)smem;             // 16 KB
        u16* sB = (u16*)(smem + 16384);   // 8 KB
        int lane = tid & 63, wave = tid >> 6;
        int wm = wave >> 1, wn = wave & 1;
        int lrow = lane & 15, g = lane >> 4;
        int bx = b & 15, by = (b >> 4) & 7, bz = b >> 7;
        int i0 = by * 128, j0 = bx * 64;
        int ktiles = ntk / 4;
        int tk0 = bz * ktiles;
        u16* outS = P.Sp + (size_t)bz * m * n;
        f32x4 acc[4][2];
        #pragma unroll
        for (int a = 0; a < 4; ++a)
            #pragma unroll
            for (int bq = 0; bq < 2; ++bq) acc[a][bq] = (f32x4){0.f, 0.f, 0.f, 0.f};
        int o = tid * 16;
        for (int tk = tk0; tk < tk0 + ktiles; ++tk) {
            const char* gA0 = (const char*)P.upw3 + (((size_t)(2 * by) * ntk + tk) << 13);
            const char* gA1 = gA0 + ((size_t)ntk << 13);
            const char* gB = (const char*)P.ucb + (((size_t)bx * ntk + tk) << 13);
            gl16(gA0 + o, (char*)sA + o);
            gl16(gA0 + 4096 + o, (char*)sA + 4096 + o);
            gl16(gA1 + o, (char*)sA + 8192 + o);
            gl16(gA1 + 4096 + o, (char*)sA + 12288 + o);
            gl16(gB + o, (char*)sB + o);
            gl16(gB + 4096 + o, (char*)sB + 4096 + o);
            __syncthreads();
            #pragma unroll
            for (int kk = 0; kk < 2; ++kk) {
                bf16x8 af[4], bf[2];
                #pragma unroll
                for (int mr = 0; mr < 4; ++mr) {
                    int row = wm * 64 + mr * 16 + lrow;
                    int boff = (row * 128 + kk * 64 + g * 16) ^ ((row & 7) << 4);
                    af[mr] = *(const bf16x8*)((const char*)sA + boff);
                }
                #pragma unroll
                for (int nr = 0; nr < 2; ++nr) {
                    int row = wn * 32 + nr * 16 + lrow;
                    int boff = (row * 128 + kk * 64 + g * 16) ^ ((row & 7) << 4);
                    bf[nr] = *(const bf16x8*)((const char*)sB + boff);
                }
                #pragma unroll
                for (int mr = 0; mr < 4; ++mr)
                    #pragma unroll
                    for (int nr = 0; nr < 2; ++nr)
                        acc[mr][nr] = __builtin_amdgcn_mfma_f32_16x16x32_bf16(af[mr], bf[nr], acc[mr][nr], 0, 0, 0);
            }
            __syncthreads();
        }
        int crow = (lane >> 4) * 4;
        int ccol = lane & 15;
        #pragma unroll
        for (int mr = 0; mr < 4; ++mr)
            #pragma unroll
            for (int nr = 0; nr < 2; ++nr) {
                int jc = j0 + wn * 32 + nr * 16 + ccol;
                #pragma unroll
                for (int jr = 0; jr < 4; ++jr) {
                    int i = i0 + wm * 64 + mr * 16 + crow + jr;
                    outS[(size_t)i * n + jc] = f2bf(acc[mr][nr][jr]);
                }
            }
    }
    __threadfence();
    grid.sync();

    // ================= phase 3: stats2 (blocks 0..255) =================
    if (b < 256) {
        float* t = (float*)smem;                 // 64*65
        float* rl = (float*)(smem + 16640);      // 64
        float* cl = (float*)(smem + 16896);      // 64
        int r0 = (b >> 4) * 64, c0 = (b & 15) * 64;
        size_t mn = (size_t)m * n;
        if (tid < 64) {
            float a = 0.f;
            for (int kc = 0; kc < ntk; ++kc) a += P.rpart[(size_t)kc * m + r0 + tid];
            rl[tid] = a;
        } else if (tid < 128) {
            int j = tid - 64;
            float a = 0.f;
            for (int kc = 0; kc < ntk; ++kc) a += P.cpart[(size_t)kc * n + c0 + j];
            cl[j] = a;
        }
        __syncthreads();
        int row = tid >> 2, seg = tid & 3;
        size_t base = (size_t)(r0 + row) * n + c0 + seg * 16;
        float s[16];
        #pragma unroll
        for (int e = 0; e < 16; ++e) s[e] = 0.f;
        #pragma unroll
        for (int z = 0; z < 4; ++z) {
            const u16* sp = P.Sp + (size_t)z * mn + base;
            int4 q0 = *(const int4*)(sp);
            int4 q1 = *(const int4*)(sp + 8);
            const u16* p0 = (const u16*)&q0;
            const u16* p1 = (const u16*)&q1;
            #pragma unroll
            for (int e = 0; e < 8; ++e) { s[e] += bf2f(p0[e]); s[8 + e] += bf2f(p1[e]); }
        }
        float rv = rl[row];
        float racc = 0.f;
        u16 h[16];
        #pragma unroll
        for (int e = 0; e < 16; ++e) {
            int col = seg * 16 + e;
            float ex = __expf(s[e] + rv + cl[col]);
            h[e] = f2bf(ex);
            float er = bf2f(h[e]);
            racc += er;
            t[col * 65 + row] = er;
        }
        char* Ebase = (char*)P.E + (((size_t)(r0 >> 6) * (n >> 6) + (c0 >> 6)) << 13);
        #pragma unroll
        for (int g = 0; g < 4; ++g) {
            int cl4 = seg * 16 + g * 4;
            int pl = (cl4 & ~31) + pos32(cl4 & 31);
            *(u16x4*)(Ebase + row * 128 + (((pl >> 3) << 4) ^ ((row & 7) << 4)) + (pl & 7) * 2) = *(u16x4*)&h[g * 4];
        }
        racc += __shfl_xor(racc, 1);
        racc += __shfl_xor(racc, 2);
        if (seg == 0) unsafeAtomicAdd(P.rowsum + r0 + row, racc);
        __syncthreads();
        int col = tid >> 2, rseg = tid & 3;
        float cacc = 0.f;
        u16 hv[16];
        #pragma unroll
        for (int rr = 0; rr < 16; ++rr) {
            float val = t[col * 65 + rseg * 16 + rr];
            cacc += val;
            hv[rr] = f2bf(val);
        }
        cacc += __shfl_xor(cacc, 1);
        cacc += __shfl_xor(cacc, 2);
        if (rseg == 0) unsafeAtomicAdd(P.colsum + c0 + col, cacc);
        char* ETbase = (char*)P.ET + (((size_t)(c0 >> 6) * (m >> 6) + (r0 >> 6)) << 13);
        #pragma unroll
        for (int g = 0; g < 4; ++g) {
            int il = rseg * 16 + g * 4;
            int pl = (il & ~31) + pos32(il & 31);
            *(u16x4*)(ETbase + col * 128 + (((pl >> 3) << 4) ^ ((col & 7) << 4)) + (pl & 7) * 2) = *(u16x4*)&hv[g * 4];
        }
    }
    __threadfence();
    grid.sync();

    // ================= phase 4: attn GEMMs + fused FFN-dot epilogue =================
    {
        u16* sA = (u16*)smem;
        u16* sB = (u16*)(smem + 16384);
        float* red = (float*)(smem + 24576);
        int lane = tid & 63, wave = tid >> 6;
        int wm = wave >> 1, wn = wave & 1;
        int lrow = lane & 15, g = lane >> 4;
        int bx = b & 31, by = (b >> 5) & 7, bz = b >> 8;
        int i0 = by * 128, kc0 = bx * 64;
        const u16* A; const u16* B; const float* sums;
        if (bz == 0) { A = P.E;  B = P.ucT; sums = P.rowsum; }
        else         { A = P.ET; B = P.upT; sums = P.colsum; }
        int ntj = n >> 6;  // m == n
        f32x4 acc[4][2];
        #pragma unroll
        for (int a = 0; a < 4; ++a)
            #pragma unroll
            for (int bq = 0; bq < 2; ++bq) acc[a][bq] = (f32x4){0.f, 0.f, 0.f, 0.f};
        int o = tid * 16;
        for (int tj = 0; tj < ntj; ++tj) {
            const char* gA0 = (const char*)A + (((size_t)(2 * by) * ntj + tj) << 13);
            const char* gA1 = gA0 + ((size_t)ntj << 13);
            const char* gB = (const char*)B + (((size_t)bx * ntj + tj) << 13);
            gl16(gA0 + o, (char*)sA + o);
            gl16(gA0 + 4096 + o, (char*)sA + 4096 + o);
            gl16(gA1 + o, (char*)sA + 8192 + o);
            gl16(gA1 + 4096 + o, (char*)sA + 12288 + o);
            gl16(gB + o, (char*)sB + o);
            gl16(gB + 4096 + o, (char*)sB + 4096 + o);
            __syncthreads();
            #pragma unroll
            for (int kk = 0; kk < 2; ++kk) {
                bf16x8 af[4], bf[2];
                #pragma unroll
                for (int mr = 0; mr < 4; ++mr) {
                    int row = wm * 64 + mr * 16 + lrow;
                    int boff = (row * 128 + kk * 64 + g * 16) ^ ((row & 7) << 4);
                    af[mr] = *(const bf16x8*)((const char*)sA + boff);
                }
                #pragma unroll
                for (int nr = 0; nr < 2; ++nr) {
                    int row = wn * 32 + nr * 16 + lrow;
                    int boff = (row * 128 + kk * 64 + g * 16) ^ ((row & 7) << 4);
                    bf[nr] = *(const bf16x8*)((const char*)sB + boff);
                }
                #pragma unroll
                for (int mr = 0; mr < 4; ++mr)
                    #pragma unroll
                    for (int nr = 0; nr < 2; ++nr)
                        acc[mr][nr] = __builtin_amdgcn_mfma_f32_16x16x32_bf16(af[mr], bf[nr], acc[mr][nr], 0, 0, 0);
            }
            __syncthreads();
        }
        int crow = (lane >> 4) * 4;
        int ccol = lane & 15;
        float tsum = 0.f;
        if (bz == 0) {
            #pragma unroll
            for (int mr = 0; mr < 4; ++mr)
                #pragma unroll
                for (int jr = 0; jr < 4; ++jr) {
                    int i = i0 + wm * 64 + mr * 16 + crow + jr;
                    float inv = 1.f / sums[i];
                    const float* wr = P.W + (size_t)i * 4 * d;
                    const float* upr = P.up + (size_t)i * d;
                    #pragma unroll
                    for (int nr = 0; nr < 2; ++nr) {
                        int kc = kc0 + wn * 32 + nr * 16 + ccol;
                        float aa = acc[mr][nr][jr] * inv;
                        tsum += aa * (wr[d + kc] + upr[kc] * wr[2 * d + kc]);
                    }
                }
        } else {
            #pragma unroll
            for (int mr = 0; mr < 4; ++mr)
                #pragma unroll
                for (int jr = 0; jr < 4; ++jr) {
                    int j = i0 + wm * 64 + mr * 16 + crow + jr;
                    float inv = 1.f / sums[j];
                    const float* wr = P.W + (size_t)j * 4 * d;
                    const float* ucr = P.uc + (size_t)j * d;
                    #pragma unroll
                    for (int nr = 0; nr < 2; ++nr) {
                        int kc = kc0 + wn * 32 + nr * 16 + ccol;
                        float ab = acc[mr][nr][jr] * inv;
                        tsum += ab * ucr[kc] * wr[3 * d + kc];
                    }
                }
        }
        red[tid] = tsum;
        __syncthreads();
        for (int s = TPB / 2; s > 0; s >>= 1) {
            if (tid < s) red[tid] += red[tid + s];
            __syncthreads();
        }
        if (tid == 0) P.fpart2[b] = red[0];
    }
    __threadfence();
    grid.sync();

    // ================= phase 5: final reduce (block 0) =================
    if (b == 0) {
        __shared__ double dred[TPB];
        double a = 0.0;
        for (int i = tid; i < 1024; i += TPB) a += (double)P.fpart[i];  // fpart||fpart2
        dred[tid] = a;
        __syncthreads();
        for (int s = TPB / 2; s > 0; s >>= 1) {
            if (tid < s) dred[tid] += dred[tid + s];
            __syncthreads();
        }
        if (tid == 0) {
            double v = dred[0] + (double)P.bias[0];
            P.out[0] = (float)(v > 0.0 ? v : 0.0);
        }
    }
}

extern "C" void kernel_launch(void* const* d_in, const int* in_sizes, int n_in,
                              void* d_out, int out_size, void* d_ws, size_t ws_size,
                              hipStream_t stream) {
    const float* u_p = (const float*)d_in[0];
    const float* u_c = (const float*)d_in[1];
    const float* w_a = (const float*)d_in[2];
    const float* ffn_w = (const float*)d_in[3];
    const float* ffn_b = (const float*)d_in[4];
    float* out = (float*)d_out;

    int d = in_sizes[2] / 3;   // 2048
    int m = in_sizes[0] / d;   // 1024
    int n = in_sizes[1] / d;   // 1024  (assumes m == n)
    const int KSPLIT = 4;
    int nkc = d / 64;          // 32

    size_t md = (size_t)m * d, nd = (size_t)n * d, mn = (size_t)m * n;

    float* ws = (float*)d_ws;
    float* rowsum = ws;                       // m  } zbuf
    float* colsum = rowsum + m;               // n  }
    float* rpart = colsum + n;                // nkc*m
    float* cpart = rpart + (size_t)nkc * m;   // nkc*n
    float* fpart = cpart + (size_t)nkc * n;   // 512 (term1) — contiguous with fpart2
    float* fpart2 = fpart + 512;              // 512 (terms 2,3)
    u16* Sp = (u16*)(fpart2 + 512);           // KSPLIT*mn
    u16* E = Sp + (size_t)KSPLIT * mn;        // mn (TBS)
    u16* ET = E + mn;                         // mn (TBS)
    u16* upw3 = ET + mn;                      // md (TBS)
    u16* ucb = upw3 + md;                     // nd (TBS)
    u16* ucT = ucb + nd;                      // nd (TBS)
    u16* upT = ucT + nd;                      // md (TBS)

    MegaParams P;
    P.up = u_p; P.uc = u_c; P.wa = w_a; P.W = ffn_w;
    P.upw3 = upw3; P.ucb = ucb; P.ucT = ucT; P.upT = upT;
    P.rpart = rpart; P.cpart = cpart; P.zbuf = rowsum; P.fpart = fpart; P.fpart2 = fpart2;
    P.Sp = Sp; P.E = E; P.ET = ET;
    P.rowsum = rowsum; P.colsum = colsum;
    P.bias = ffn_b; P.out = out;
    P.m = m; P.n = n; P.d = d;

    void* args[] = {&P};
    hipLaunchCooperativeKernel((void*)mega_kernel, dim3(512), dim3(TPB), args, 0, stream);

    (void)out_size; (void)ws_size; (void)n_in;
}

// Round 13
// 51.208 us; speedup vs baseline: 9.2084x; 9.2084x over previous
//
#include <hip/hip_runtime.h>
#include <math.h>

#define TPB 256

typedef unsigned short u16;
typedef short bf16x8 __attribute__((ext_vector_type(8)));
typedef unsigned short u16x4 __attribute__((ext_vector_type(4)));
typedef float f32x4 __attribute__((ext_vector_type(4)));

__device__ __forceinline__ u16 f2bf(float x) {
    unsigned u = __float_as_uint(x);
    unsigned r = u + 0x7fffu + ((u >> 16) & 1u);
    return (u16)(r >> 16);
}
__device__ __forceinline__ float bf2f(u16 h) {
    return __uint_as_float(((unsigned)h) << 16);
}
// k-permutation within 32-chunk (half-split fragment layout); applied to BOTH
// operands of every GEMM -> dot over k is permutation-invariant.
__device__ __forceinline__ int pos32(int kk) {
    return ((kk >> 2) & 3) * 8 + (kk >> 4) * 4 + (kk & 3);
}
__device__ __forceinline__ int ipos32(int p5) {
    return 16 * ((p5 >> 2) & 1) + 4 * (p5 >> 3) + (p5 & 3);
}

// Tile-blocked-swizzled (TBS) storage: matrix[R][K] bf16 as 64x64 tiles, tile
// (tr,tk) = 8 KB at ((tr*(K/64)+tk)<<13); element (row,p) at byte
// row*128 + (((p>>3)<<4) ^ ((row&7)<<4)) + (p&7)*2  == the LDS image.

#if defined(__has_builtin)
#if __has_builtin(__builtin_amdgcn_global_load_lds)
#define HAS_GLL 1
#endif
#endif
#ifndef HAS_GLL
#define HAS_GLL 0
#endif

__device__ __forceinline__ void gl16(const char* g, char* l) {
#if HAS_GLL
    __builtin_amdgcn_global_load_lds(
        (const __attribute__((address_space(1))) void*)(unsigned long long)g,
        (__attribute__((address_space(3))) void*)(unsigned int)(unsigned long long)l,
        16, 0, 0);
#else
    *(int4*)l = *(const int4*)g;
#endif
}

// ---------------- kernel 1: prep = transpose+convert (TBS) + bias partials + term1 ----------------
__global__ __launch_bounds__(TPB) void prep_kernel(
    const float* __restrict__ up, const float* __restrict__ uc,
    const float* __restrict__ wa, const float* __restrict__ W,
    u16* __restrict__ upw3, u16* __restrict__ ucb,
    u16* __restrict__ ucT, u16* __restrict__ upT,
    float* __restrict__ rpart, float* __restrict__ cpart,
    float* __restrict__ zbuf, float* __restrict__ fpart,
    int m, int n, int d, int nTc) {
    __shared__ float t[64 * 65];
    __shared__ float wred[4];
    int b = blockIdx.x, tid = threadIdx.x;
    if (b < 8) {  // zero rowsum/colsum (consumers in later kernels)
        int idx = b * TPB + tid;
        if (idx < 2 * m) zbuf[idx] = 0.f;
    }
    const float* src; u16* dstT; u16* dstR; float* bpart; int rows; int tt; int isUp;
    if (b < nTc) { src = uc; dstT = ucT; dstR = ucb;  bpart = cpart; rows = n; tt = b;       isUp = 0; }
    else         { src = up; dstT = upT; dstR = upw3; bpart = rpart; rows = m; tt = b - nTc; isUp = 1; }
    int ntx = d / 64;
    int c0 = (tt % ntx) * 64;   // k-range
    int r0 = (tt / ntx) * 64;   // sample-row range

    // load tile into LDS transposed: t[k_local][row_local]
    #pragma unroll
    for (int it = 0; it < 4; ++it) {
        int rr = (tid >> 4) + it * 16;
        int cc = (tid & 15) * 4;
        float4 v = *(const float4*)(src + (size_t)(r0 + rr) * d + c0 + cc);
        t[(cc + 0) * 65 + rr] = v.x;
        t[(cc + 1) * 65 + rr] = v.y;
        t[(cc + 2) * 65 + rr] = v.z;
        t[(cc + 3) * 65 + rr] = v.w;
    }
    __syncthreads();
    // phase 2: transposed TBS output dstT (rows of dstT = k; cols = sample, permuted)
    {
        char* tbase = (char*)dstT + (((size_t)(c0 >> 6) * (rows >> 6) + (r0 >> 6)) << 13);
        #pragma unroll
        for (int it = 0; it < 2; ++it) {
            int id = tid + it * TPB;
            int kc = id >> 3;
            int s = id & 7;
            u16 outv[8];
            #pragma unroll
            for (int e = 0; e < 8; ++e) {
                int p = s * 8 + e;
                int jloc = 32 * (p >> 5) + ipos32(p & 31);
                outv[e] = f2bf(t[kc * 65 + jloc]);
            }
            char* pp = tbase + kc * 128 + ((s * 16) ^ ((kc & 7) << 4));
            *(u16x4*)pp = *(u16x4*)&outv[0];
            *(u16x4*)(pp + 8) = *(u16x4*)&outv[4];
        }
    }
    // phase 3: row-major TBS output dstR (k permuted), *w3 for up
    {
        char* rbase = (char*)dstR + (((size_t)(r0 >> 6) * (d >> 6) + (c0 >> 6)) << 13);
        int rr = tid >> 2;
        int cbase = (tid & 3) * 16;
        #pragma unroll
        for (int grp = 0; grp < 4; ++grp) {
            int kl = cbase + grp * 4;
            u16x4 o;
            #pragma unroll
            for (int e = 0; e < 4; ++e) {
                float val = t[(kl + e) * 65 + rr];
                if (isUp) val *= wa[2 * d + c0 + kl + e];
                o[e] = f2bf(val);
            }
            int pl = (kl & ~31) + pos32(kl & 31);
            *(u16x4*)(rbase + rr * 128 + (((pl >> 3) << 4) ^ ((rr & 7) << 4)) + (pl & 7) * 2) = o;
        }
    }
    // phase 4: bias partials bpart[kchunk][row] = sum_k tile[row,k]*w{1,2}[k]
    {
        int rr = tid >> 2;
        int kseg = tid & 3;
        const float* w = wa + (isUp ? 0 : d) + c0;
        float acc = 0.f;
        #pragma unroll
        for (int kk = 0; kk < 16; ++kk) {
            int k = kseg * 16 + kk;
            acc += t[k * 65 + rr] * w[k];
        }
        acc += __shfl_xor(acc, 1);
        acc += __shfl_xor(acc, 2);
        if (kseg == 0) bpart[(size_t)(c0 >> 6) * rows + r0 + rr] = acc;
    }
    // phase 5 (up tiles only): term1 partial = sum tile[rr,k]*W0[r0+rr, c0+k]
    if (isUp) {
        int rr = tid >> 2;
        int kseg = tid & 3;
        const float* w0r = W + (size_t)(r0 + rr) * 4 * d + c0 + kseg * 16;
        float acc = 0.f;
        #pragma unroll
        for (int kk = 0; kk < 16; ++kk) acc += t[(kseg * 16 + kk) * 65 + rr] * w0r[kk];
        #pragma unroll
        for (int off = 32; off > 0; off >>= 1) acc += __shfl_down(acc, off);
        if ((tid & 63) == 0) wred[tid >> 6] = acc;
        __syncthreads();
        if (tid == 0) fpart[tt] = wred[0] + wred[1] + wred[2] + wred[3];
    }
}

// ---------------- kernel 2: gemmS partials (bf16): Sp[z] = upw3 @ ucb^T, 128x64 tile,
//                  double-buffered global_load_lds staging (T3-minimum) ----------------
__global__ __launch_bounds__(TPB) void gemmS_mfma(
    const u16* __restrict__ Ah, const u16* __restrict__ Bh,
    u16* __restrict__ Sp, int m, int n, int d, int ksplit) {
    __shared__ u16 sA[2 * 128 * 64];  // 2 x 16 KB
    __shared__ u16 sB[2 * 64 * 64];   // 2 x 8 KB
    int tid = threadIdx.x;
    int lane = tid & 63, wave = tid >> 6;
    int wm = wave >> 1, wn = wave & 1;
    int lrow = lane & 15, g = lane >> 4;
    int by = blockIdx.y, bx = blockIdx.x;
    int i0 = by * 128, j0 = bx * 64;
    int ntk = d >> 6;
    int ktiles = ntk / ksplit;
    int tk0 = blockIdx.z * ktiles;
    u16* outS = Sp + (size_t)blockIdx.z * m * n;
    f32x4 acc[4][2];
    #pragma unroll
    for (int a = 0; a < 4; ++a)
        #pragma unroll
        for (int bq = 0; bq < 2; ++bq) acc[a][bq] = (f32x4){0.f, 0.f, 0.f, 0.f};

    int o = tid * 16;
    auto stage = [&](int buf, int tk) {
        const char* gA0 = (const char*)Ah + (((size_t)(2 * by) * ntk + tk) << 13);
        const char* gA1 = gA0 + ((size_t)ntk << 13);
        const char* gB = (const char*)Bh + (((size_t)bx * ntk + tk) << 13);
        char* lA = (char*)sA + buf * 16384;
        char* lB = (char*)sB + buf * 8192;
        gl16(gA0 + o, lA + o);
        gl16(gA0 + 4096 + o, lA + 4096 + o);
        gl16(gA1 + o, lA + 8192 + o);
        gl16(gA1 + 4096 + o, lA + 12288 + o);
        gl16(gB + o, lB + o);
        gl16(gB + 4096 + o, lB + 4096 + o);
    };

    stage(0, tk0);
    __syncthreads();
    int cur = 0;
    for (int tk = tk0; tk < tk0 + ktiles; ++tk) {
        if (tk + 1 < tk0 + ktiles) stage(cur ^ 1, tk + 1);  // async prefetch overlaps MFMA
        const char* lA = (const char*)sA + cur * 16384;
        const char* lB = (const char*)sB + cur * 8192;
        #pragma unroll
        for (int kk = 0; kk < 2; ++kk) {
            bf16x8 af[4], bf[2];
            #pragma unroll
            for (int mr = 0; mr < 4; ++mr) {
                int row = wm * 64 + mr * 16 + lrow;
                int boff = (row * 128 + kk * 64 + g * 16) ^ ((row & 7) << 4);
                af[mr] = *(const bf16x8*)(lA + boff);
            }
            #pragma unroll
            for (int nr = 0; nr < 2; ++nr) {
                int row = wn * 32 + nr * 16 + lrow;
                int boff = (row * 128 + kk * 64 + g * 16) ^ ((row & 7) << 4);
                bf[nr] = *(const bf16x8*)(lB + boff);
            }
            #pragma unroll
            for (int mr = 0; mr < 4; ++mr)
                #pragma unroll
                for (int nr = 0; nr < 2; ++nr)
                    acc[mr][nr] = __builtin_amdgcn_mfma_f32_16x16x32_bf16(af[mr], bf[nr], acc[mr][nr], 0, 0, 0);
        }
        __syncthreads();  // drains prefetch (vmcnt) + read completion; 1 barrier/iter
        cur ^= 1;
    }
    int crow = (lane >> 4) * 4;
    int ccol = lane & 15;
    #pragma unroll
    for (int mr = 0; mr < 4; ++mr)
        #pragma unroll
        for (int nr = 0; nr < 2; ++nr) {
            int jc = j0 + wn * 32 + nr * 16 + ccol;
            #pragma unroll
            for (int jr = 0; jr < 4; ++jr) {
                int i = i0 + wm * 64 + mr * 16 + crow + jr;
                outS[(size_t)i * n + jc] = f2bf(acc[mr][nr][jr]);
            }
        }
}

// ---------------- kernel 3: stats2 = E=exp(sum(Sp)+r+c) -> E,ET in TBS bf16; rowsum/colsum atomics ----------------
__global__ __launch_bounds__(TPB) void stats2_kernel(
    const u16* __restrict__ Sp, const float* __restrict__ rpart, const float* __restrict__ cpart,
    u16* __restrict__ E, u16* __restrict__ ET,
    float* __restrict__ rowsum, float* __restrict__ colsum,
    int m, int n) {
    __shared__ float t[64 * 65];
    __shared__ float rl[64], cl[64];
    int tid = threadIdx.x;
    int r0 = blockIdx.y * 64, c0 = blockIdx.x * 64;
    size_t mn = (size_t)m * n;
    int nkc = 32;  // d/64 bias partial chunks
    if (tid < 64) {
        float a = 0.f;
        for (int kc = 0; kc < nkc; ++kc) a += rpart[(size_t)kc * m + r0 + tid];
        rl[tid] = a;
    } else if (tid < 128) {
        int j = tid - 64;
        float a = 0.f;
        for (int kc = 0; kc < nkc; ++kc) a += cpart[(size_t)kc * n + c0 + j];
        cl[j] = a;
    }
    __syncthreads();
    int row = tid >> 2, seg = tid & 3;
    size_t base = (size_t)(r0 + row) * n + c0 + seg * 16;
    float s[16];
    #pragma unroll
    for (int e = 0; e < 16; ++e) s[e] = 0.f;
    #pragma unroll
    for (int z = 0; z < 4; ++z) {
        const u16* sp = Sp + (size_t)z * mn + base;
        int4 q0 = *(const int4*)(sp);
        int4 q1 = *(const int4*)(sp + 8);
        const u16* p0 = (const u16*)&q0;
        const u16* p1 = (const u16*)&q1;
        #pragma unroll
        for (int e = 0; e < 8; ++e) { s[e] += bf2f(p0[e]); s[8 + e] += bf2f(p1[e]); }
    }
    float rv = rl[row];
    float racc = 0.f;
    u16 h[16];
    #pragma unroll
    for (int e = 0; e < 16; ++e) {
        int col = seg * 16 + e;
        float ex = __expf(s[e] + rv + cl[col]);
        h[e] = f2bf(ex);
        float er = bf2f(h[e]);
        racc += er;
        t[col * 65 + row] = er;
    }
    // E (TBS): rows=i, cols=j permuted
    char* Ebase = (char*)E + (((size_t)(r0 >> 6) * (n >> 6) + (c0 >> 6)) << 13);
    #pragma unroll
    for (int g = 0; g < 4; ++g) {
        int cl4 = seg * 16 + g * 4;
        int pl = (cl4 & ~31) + pos32(cl4 & 31);
        *(u16x4*)(Ebase + row * 128 + (((pl >> 3) << 4) ^ ((row & 7) << 4)) + (pl & 7) * 2) = *(u16x4*)&h[g * 4];
    }
    racc += __shfl_xor(racc, 1);
    racc += __shfl_xor(racc, 2);
    if (seg == 0) unsafeAtomicAdd(rowsum + r0 + row, racc);
    __syncthreads();
    // ET (TBS): rows=j, cols=i permuted; + colsum
    int col = tid >> 2, rseg = tid & 3;
    float cacc = 0.f;
    u16 hv[16];
    #pragma unroll
    for (int rr = 0; rr < 16; ++rr) {
        float val = t[col * 65 + rseg * 16 + rr];
        cacc += val;
        hv[rr] = f2bf(val);
    }
    cacc += __shfl_xor(cacc, 1);
    cacc += __shfl_xor(cacc, 2);
    if (rseg == 0) unsafeAtomicAdd(colsum + c0 + col, cacc);
    char* ETbase = (char*)ET + (((size_t)(c0 >> 6) * (m >> 6) + (r0 >> 6)) << 13);
    #pragma unroll
    for (int g = 0; g < 4; ++g) {
        int il = rseg * 16 + g * 4;
        int pl = (il & ~31) + pos32(il & 31);
        *(u16x4*)(ETbase + col * 128 + (((pl >> 3) << 4) ^ ((col & 7) << 4)) + (pl & 7) * 2) = *(u16x4*)&hv[g * 4];
    }
}

// ---------------- kernel 4: attn = two bf16 GEMMs, double-buffered gload staging,
//                  fused FFN-dot epilogue ----------------
__global__ __launch_bounds__(TPB) void attn_mfma(
    const u16* __restrict__ E, const u16* __restrict__ ET,
    const u16* __restrict__ ucT, const u16* __restrict__ upT,
    const float* __restrict__ up, const float* __restrict__ uc,
    const float* __restrict__ W,
    const float* __restrict__ rowsum, const float* __restrict__ colsum,
    float* __restrict__ fpart2, int m, int n, int d) {
    __shared__ u16 sA[2 * 128 * 64];
    __shared__ u16 sB[2 * 64 * 64];
    __shared__ float red[TPB];
    int tid = threadIdx.x;
    int lane = tid & 63, wave = tid >> 6;
    int wm = wave >> 1, wn = wave & 1;
    int lrow = lane & 15, g = lane >> 4;
    int by = blockIdx.y, bx = blockIdx.x, bz = blockIdx.z;
    int i0 = by * 128, kc0 = bx * 64;
    const u16* A; const u16* B; const float* sums; int kT;
    if (bz == 0) { A = E;  B = ucT; sums = rowsum; kT = n; }
    else         { A = ET; B = upT; sums = colsum; kT = m; }
    int ntk = kT >> 6;
    f32x4 acc[4][2];
    #pragma unroll
    for (int a = 0; a < 4; ++a)
        #pragma unroll
        for (int bq = 0; bq < 2; ++bq) acc[a][bq] = (f32x4){0.f, 0.f, 0.f, 0.f};

    int o = tid * 16;
    auto stage = [&](int buf, int tj) {
        const char* gA0 = (const char*)A + (((size_t)(2 * by) * ntk + tj) << 13);
        const char* gA1 = gA0 + ((size_t)ntk << 13);
        const char* gB = (const char*)B + (((size_t)bx * ntk + tj) << 13);
        char* lA = (char*)sA + buf * 16384;
        char* lB = (char*)sB + buf * 8192;
        gl16(gA0 + o, lA + o);
        gl16(gA0 + 4096 + o, lA + 4096 + o);
        gl16(gA1 + o, lA + 8192 + o);
        gl16(gA1 + 4096 + o, lA + 12288 + o);
        gl16(gB + o, lB + o);
        gl16(gB + 4096 + o, lB + 4096 + o);
    };

    stage(0, 0);
    __syncthreads();
    int cur = 0;
    for (int tj = 0; tj < ntk; ++tj) {
        if (tj + 1 < ntk) stage(cur ^ 1, tj + 1);
        const char* lA = (const char*)sA + cur * 16384;
        const char* lB = (const char*)sB + cur * 8192;
        #pragma unroll
        for (int kk = 0; kk < 2; ++kk) {
            bf16x8 af[4], bf[2];
            #pragma unroll
            for (int mr = 0; mr < 4; ++mr) {
                int row = wm * 64 + mr * 16 + lrow;
                int boff = (row * 128 + kk * 64 + g * 16) ^ ((row & 7) << 4);
                af[mr] = *(const bf16x8*)(lA + boff);
            }
            #pragma unroll
            for (int nr = 0; nr < 2; ++nr) {
                int row = wn * 32 + nr * 16 + lrow;
                int boff = (row * 128 + kk * 64 + g * 16) ^ ((row & 7) << 4);
                bf[nr] = *(const bf16x8*)(lB + boff);
            }
            #pragma unroll
            for (int mr = 0; mr < 4; ++mr)
                #pragma unroll
                for (int nr = 0; nr < 2; ++nr)
                    acc[mr][nr] = __builtin_amdgcn_mfma_f32_16x16x32_bf16(af[mr], bf[nr], acc[mr][nr], 0, 0, 0);
        }
        __syncthreads();
        cur ^= 1;
    }
    int crow = (lane >> 4) * 4;
    int ccol = lane & 15;
    float tsum = 0.f;
    if (bz == 0) {
        // term2: aalpha[i,kc] * (W1[i,kc] + up[i,kc]*W2[i,kc])
        #pragma unroll
        for (int mr = 0; mr < 4; ++mr)
            #pragma unroll
            for (int jr = 0; jr < 4; ++jr) {
                int i = i0 + wm * 64 + mr * 16 + crow + jr;
                float inv = 1.f / sums[i];
                const float* wr = W + (size_t)i * 4 * d;
                const float* upr = up + (size_t)i * d;
                #pragma unroll
                for (int nr = 0; nr < 2; ++nr) {
                    int kc = kc0 + wn * 32 + nr * 16 + ccol;
                    float aa = acc[mr][nr][jr] * inv;
                    tsum += aa * (wr[d + kc] + upr[kc] * wr[2 * d + kc]);
                }
            }
    } else {
        // term3: abeta[j,kc] * uc[j,kc] * W3[j,kc]
        #pragma unroll
        for (int mr = 0; mr < 4; ++mr)
            #pragma unroll
            for (int jr = 0; jr < 4; ++jr) {
                int j = i0 + wm * 64 + mr * 16 + crow + jr;
                float inv = 1.f / sums[j];
                const float* wr = W + (size_t)j * 4 * d;
                const float* ucr = uc + (size_t)j * d;
                #pragma unroll
                for (int nr = 0; nr < 2; ++nr) {
                    int kc = kc0 + wn * 32 + nr * 16 + ccol;
                    float ab = acc[mr][nr][jr] * inv;
                    tsum += ab * ucr[kc] * wr[3 * d + kc];
                }
            }
    }
    red[tid] = tsum;
    __syncthreads();
    for (int s = TPB / 2; s > 0; s >>= 1) {
        if (tid < s) red[tid] += red[tid + s];
        __syncthreads();
    }
    if (tid == 0)
        fpart2[(size_t)bz * gridDim.x * gridDim.y + (size_t)by * gridDim.x + bx] = red[0];
}

// ---------------- kernel 5: final = relu(sum(fparts) + bias) ----------------
__global__ __launch_bounds__(TPB) void final_out(
    const float* __restrict__ fparts, int cnt, const float* __restrict__ bias,
    float* __restrict__ out) {
    __shared__ double red[TPB];
    double a = 0.0;
    for (int i = threadIdx.x; i < cnt; i += TPB) a += (double)fparts[i];
    red[threadIdx.x] = a;
    __syncthreads();
    for (int s = TPB / 2; s > 0; s >>= 1) {
        if (threadIdx.x < s) red[threadIdx.x] += red[threadIdx.x + s];
        __syncthreads();
    }
    if (threadIdx.x == 0) {
        double v = red[0] + (double)bias[0];
        out[0] = (float)(v > 0.0 ? v : 0.0);
    }
}

extern "C" void kernel_launch(void* const* d_in, const int* in_sizes, int n_in,
                              void* d_out, int out_size, void* d_ws, size_t ws_size,
                              hipStream_t stream) {
    const float* u_p = (const float*)d_in[0];
    const float* u_c = (const float*)d_in[1];
    const float* w_a = (const float*)d_in[2];
    const float* ffn_w = (const float*)d_in[3];
    const float* ffn_b = (const float*)d_in[4];
    float* out = (float*)d_out;

    int d = in_sizes[2] / 3;   // 2048
    int m = in_sizes[0] / d;   // 1024
    int n = in_sizes[1] / d;   // 1024  (assumes m == n)
    const int KSPLIT = 4;
    int nkc = d / 64;          // 32

    size_t md = (size_t)m * d, nd = (size_t)n * d, mn = (size_t)m * n;
    int nTc = (d / 64) * (n / 64);   // 512
    int nTp = (d / 64) * (m / 64);   // 512
    int nF2 = 2 * (d / 64) * (m / 128);  // 512

    float* ws = (float*)d_ws;
    float* rowsum = ws;                       // m  } zbuf (zeroed in prep)
    float* colsum = rowsum + m;               // n  }
    float* rpart = colsum + n;                // nkc*m
    float* cpart = rpart + (size_t)nkc * m;   // nkc*n
    float* fpart = cpart + (size_t)nkc * n;   // nTp (term1, written by prep)
    float* fpart2 = fpart + nTp;              // nF2 (terms 2,3, written by attn)
    u16* Sp = (u16*)(fpart2 + nF2);           // KSPLIT*mn
    u16* E = Sp + (size_t)KSPLIT * mn;        // mn (TBS)
    u16* ET = E + mn;                         // mn (TBS)
    u16* upw3 = ET + mn;                      // md (TBS)
    u16* ucb = upw3 + md;                     // nd (TBS)
    u16* ucT = ucb + nd;                      // nd (TBS)
    u16* upT = ucT + nd;                      // md (TBS)

    prep_kernel<<<nTc + nTp, TPB, 0, stream>>>(
        u_p, u_c, w_a, ffn_w, upw3, ucb, ucT, upT, rpart, cpart, rowsum, fpart,
        m, n, d, nTc);

    dim3 gS(n / 64, m / 128, KSPLIT);
    gemmS_mfma<<<gS, TPB, 0, stream>>>(upw3, ucb, Sp, m, n, d, KSPLIT);

    dim3 gT(n / 64, m / 64);
    stats2_kernel<<<gT, TPB, 0, stream>>>(Sp, rpart, cpart, E, ET, rowsum, colsum, m, n);

    dim3 gA(d / 64, m / 128, 2);
    attn_mfma<<<gA, TPB, 0, stream>>>(E, ET, ucT, upT, u_p, u_c, ffn_w,
                                      rowsum, colsum, fpart2, m, n, d);

    final_out<<<1, TPB, 0, stream>>>(fpart, nTp + nF2, ffn_b, out);

    (void)out_size; (void)ws_size; (void)n_in;
}